// Round 3
// baseline (939.345 us; speedup 1.0000x reference)
//
#include <hip/hip_runtime.h>
#include <hip/hip_bf16.h>

// ---------------------------------------------------------------------------
// Set2Set pooling: 3 steps of { LSTM cell -> segment softmax attention } then
// a final projection.  B=256 graphs, N=100000 nodes, d=512.
//
// Runtime dtype detection (device-side, since the harness dtype policy is
// ambiguous): flags[0] = batch is int64, flags[1] = float arrays are fp32
// (not bf16).  All kernels branch wave-uniformly on these flags.
// ---------------------------------------------------------------------------

typedef __bf16 bf16_t;
typedef __bf16 bf16x8 __attribute__((ext_vector_type(8)));
typedef float  f32x4  __attribute__((ext_vector_type(4)));

#define D     512
#define B_GR  256
#define FOURD 2048
#define KCAT  1536
#define ECAP  12288   // LDS slots for e; ~30x expected max segment size

// ---------------------------------------------------------------------------
// flags[0]: batch int64?  (int32 view of sorted data never strictly decreases;
//           int64-as-int32 view [v,0,v',0,...] almost surely does)
// flags[1]: x fp32?  (bf16 view of fp32 bits shows |v|>=128 / NaN exponents;
//           genuine N(0,1) bf16 data never exceeds ~5)
__global__ void detect_kernel(const int* __restrict__ b32, int N,
                              const unsigned short* __restrict__ xh,
                              int* __restrict__ flags) {
    int tid = threadIdx.x;
    int dec = 0;
    for (int i = tid; i < N - 1; i += blockDim.x)
        if (b32[i] > b32[i + 1]) dec = 1;
    if (dec) atomicOr(&flags[0], 1);
    int bad = 0;
    for (int i = tid; i < 1024; i += blockDim.x) {
        unsigned e = (xh[i] >> 7) & 0xff;   // bf16 exponent field
        if (e >= 134) bad = 1;              // |v| >= 128 or NaN/Inf
    }
    if (bad) atomicOr(&flags[1], 1);
}

// ---------------------------------------------------------------------------
// segment boundaries from sorted batch ids (int32 or int64 per flags[0])
__global__ void seg_bounds_kernel(const void* __restrict__ batch, int N, int B,
                                  const int* __restrict__ flags,
                                  int* __restrict__ seg) {
    int n = blockIdx.x * blockDim.x + threadIdx.x;
    if (n >= N) return;
    const int is64 = flags[0];
    const int* b32 = (const int*)batch;
    const long long* b64 = (const long long*)batch;
    int cur = is64 ? (int)b64[n] : b32[n];
    if (n == 0) {
        for (int b = 0; b <= cur && b <= B; ++b) seg[b] = 0;
    } else {
        int prev = is64 ? (int)b64[n - 1] : b32[n - 1];
        for (int b = prev + 1; b <= cur && b <= B; ++b) seg[b] = n;
    }
    if (n == N - 1) {
        for (int b = cur + 1; b <= B; ++b) seg[b] = N;
    }
}

// ---------------------------------------------------------------------------
// dtype-polymorphic fragment / bias loads for the GEMM B-operand
__device__ __forceinline__ bf16x8 load_frag(const void* base, int ld, int row,
                                            int k, int f32) {
    if (f32) {
        const float* p = (const float*)base + (size_t)row * ld + k;
        bf16x8 r;
#pragma unroll
        for (int j = 0; j < 8; ++j) r[j] = (bf16_t)p[j];
        return r;
    }
    return *(const bf16x8*)((const bf16_t*)base + (size_t)row * ld + k);
}

__device__ __forceinline__ float load_bias(const void* b, int i, int f32) {
    return f32 ? ((const float*)b)[i] : (float)((const bf16_t*)b)[i];
}

// ---------------------------------------------------------------------------
// C = A * B^T (+bias) with MFMA 16x16x32 bf16.  A: [M][K] bf16 (ours).
// B split:  k < ksplit -> B1[n][k] (ldb1);  k >= ksplit -> B2[n][k-ksplit].
// Output: Cf only -> f32; Cf==Cb alias -> pick f32/bf16 by flags[1];
//         Cb only -> bf16.  One wave per 16x16 tile.
__global__ __launch_bounds__(64)
void gemm_bt(const bf16_t* __restrict__ A, int lda,
             const void* __restrict__ B1, int ldb1,
             const void* __restrict__ B2, int ldb2, int ksplit, int K,
             const void* __restrict__ bias1, const void* __restrict__ bias2,
             float* __restrict__ Cf, bf16_t* __restrict__ Cb, int ldc,
             const int* __restrict__ flags) {
    const int f32w  = flags[1];
    const int lane  = threadIdx.x;
    const int n0    = blockIdx.x * 16;
    const int m0    = blockIdx.y * 16;
    const int rowA  = m0 + (lane & 15);
    const int rowB  = n0 + (lane & 15);
    const int kbase = (lane >> 4) * 8;

    f32x4 acc = {0.f, 0.f, 0.f, 0.f};

    const int k1 = (ksplit < K) ? ksplit : K;
    for (int k0 = 0; k0 < k1; k0 += 32) {
        int k = k0 + kbase;
        bf16x8 a = *(const bf16x8*)(A + (size_t)rowA * lda + k);
        bf16x8 b = load_frag(B1, ldb1, rowB, k, f32w);
        acc = __builtin_amdgcn_mfma_f32_16x16x32_bf16(a, b, acc, 0, 0, 0);
    }
    for (int k0 = k1; k0 < K; k0 += 32) {
        int k = k0 + kbase;
        bf16x8 a = *(const bf16x8*)(A + (size_t)rowA * lda + k);
        bf16x8 b = load_frag(B2, ldb2, rowB, k - ksplit, f32w);
        acc = __builtin_amdgcn_mfma_f32_16x16x32_bf16(a, b, acc, 0, 0, 0);
    }

    // D layout (verified m89): col = lane&15, row = (lane>>4)*4 + reg
    const int col   = lane & 15;
    const int rbase = (lane >> 4) * 4;
    float bias = 0.f;
    if (bias1) bias += load_bias(bias1, n0 + col, f32w);
    if (bias2) bias += load_bias(bias2, n0 + col, f32w);
    const bool out_f32 = Cf && (Cb == nullptr || f32w);
#pragma unroll
    for (int r = 0; r < 4; ++r) {
        int m = m0 + rbase + r;
        int n = n0 + col;
        float v = acc[r] + bias;
        if (out_f32) Cf[(size_t)m * ldc + n] = v;
        else         Cb[(size_t)m * ldc + n] = (bf16_t)v;
    }
}

// ---------------------------------------------------------------------------
// LSTM pointwise: gates [B][2048] (i,f,g,o) -> c,h; h also written (bf16)
// into Abuf columns [0,512) and [1024,1536).
__global__ void lstm_cell(const float* __restrict__ gates,
                          float* __restrict__ c, float* __restrict__ h,
                          bf16_t* __restrict__ Abuf) {
    int idx = blockIdx.x * blockDim.x + threadIdx.x;   // B*D threads
    int b = idx >> 9, t = idx & 511;
    const float* g = gates + (size_t)b * FOURD;
    float gi = g[t], gf = g[512 + t], gg = g[1024 + t], go = g[1536 + t];
    float cv = c[idx];
    float si = 1.f / (1.f + __expf(-gi));
    float sf = 1.f / (1.f + __expf(-gf));
    float so = 1.f / (1.f + __expf(-go));
    float tg = tanhf(gg);
    float cn = sf * cv + si * tg;
    float hn = so * tanhf(cn);
    c[idx] = cn;
    h[idx] = hn;
    bf16_t hb = (bf16_t)hn;
    Abuf[(size_t)b * KCAT + t]        = hb;
    Abuf[(size_t)b * KCAT + 1024 + t] = hb;
}

// ---------------------------------------------------------------------------
// Segment softmax attention, one block (512 thr = 8 waves) per graph.
__global__ __launch_bounds__(512)
void attention_kernel(const void* __restrict__ xv_, int N,
                      const int* __restrict__ seg,
                      const float* __restrict__ hbuf,
                      float* __restrict__ e_ws,
                      bf16_t* __restrict__ Abuf,
                      const int* __restrict__ flags) {
    __shared__ float e_sh[ECAP];
    __shared__ float red_m[8], red_s[8];
    __shared__ float racc[D];

    const int f32x = flags[1];
    const int b    = blockIdx.x;
    int s  = seg[b];
    int en = seg[b + 1];
    s  = (s  < 0) ? 0 : ((s  > N) ? N : s);     // defensive clamp
    en = (en < s) ? s : ((en > N) ? N : en);
    const int cnt  = en - s;
    const int tid  = threadIdx.x;
    const int wave = tid >> 6;
    const int lane = tid & 63;

    // per-lane slice of h (8 contiguous f32); same for all waves -> L1 hot
    float hl[8];
    {
        const float* hp = hbuf + ((size_t)b << 9) + lane * 8;
#pragma unroll
        for (int j = 0; j < 8; ++j) hl[j] = hp[j];
    }

    float m_w = -INFINITY, s_w = 0.f;
    for (int i = wave; i < cnt; i += 8) {
        int n = s + i;
        float d = 0.f;
        if (f32x) {
            const float* xp = (const float*)xv_ + ((size_t)n << 9) + lane * 8;
            float4 v0 = *(const float4*)xp;
            float4 v1 = *(const float4*)(xp + 4);
            d = v0.x * hl[0] + v0.y * hl[1] + v0.z * hl[2] + v0.w * hl[3]
              + v1.x * hl[4] + v1.y * hl[5] + v1.z * hl[6] + v1.w * hl[7];
        } else {
            bf16x8 xv = *(const bf16x8*)((const bf16_t*)xv_ + ((size_t)n << 9) + lane * 8);
#pragma unroll
            for (int j = 0; j < 8; ++j) d += (float)xv[j] * hl[j];
        }
#pragma unroll
        for (int off = 32; off > 0; off >>= 1) d += __shfl_xor(d, off, 64);
        // online softmax (all lanes hold identical d)
        if (d > m_w) { s_w = s_w * __expf(m_w - d) + 1.f; m_w = d; }
        else         { s_w += __expf(d - m_w); }
        if (lane == 0) {
            if (i < ECAP) e_sh[i] = d;
            else          e_ws[n] = d;
        }
    }
    if (lane == 0) { red_m[wave] = m_w; red_s[wave] = s_w; }
    __syncthreads();

    float M = -INFINITY, S = 0.f;
#pragma unroll
    for (int w = 0; w < 8; ++w)
        if (red_s[w] > 0.f) M = fmaxf(M, red_m[w]);
#pragma unroll
    for (int w = 0; w < 8; ++w)
        if (red_s[w] > 0.f) S += red_s[w] * __expf(red_m[w] - M);
    float Sinv = 1.f / (S + 1e-16f);

    // Phase 2: two groups of 256 threads split the nodes; thread -> dim pair.
    const int group = tid >> 8;
    const int tt    = tid & 255;
    float a0 = 0.f, a1 = 0.f;
    for (int i = group; i < cnt; i += 2) {
        int n = s + i;
        float ev = (i < ECAP) ? e_sh[i] : e_ws[n];
        float w  = __expf(ev - M) * Sinv;
        if (f32x) {
            const float* xp = (const float*)xv_ + ((size_t)n << 9) + tt * 2;
            a0 += w * xp[0];
            a1 += w * xp[1];
        } else {
            unsigned u = *(const unsigned*)((const bf16_t*)xv_ + ((size_t)n << 9) + tt * 2);
            a0 += w * __uint_as_float(u << 16);
            a1 += w * __uint_as_float(u & 0xffff0000u);
        }
    }
    if (group == 1) { racc[tt * 2] = a0; racc[tt * 2 + 1] = a1; }
    __syncthreads();
    if (group == 0) {
        float t0 = a0 + racc[tt * 2];
        float t1 = a1 + racc[tt * 2 + 1];
        size_t ab = (size_t)b * KCAT + 512 + tt * 2;   // r -> A cols [512,1024)
        Abuf[ab]     = (bf16_t)t0;
        Abuf[ab + 1] = (bf16_t)t1;
    }
}

// ---------------------------------------------------------------------------
extern "C" void kernel_launch(void* const* d_in, const int* in_sizes, int n_in,
                              void* d_out, int out_size, void* d_ws, size_t ws_size,
                              hipStream_t stream) {
    const void* x      = d_in[0];
    const void* batch  = d_in[1];
    const void* W_ih   = d_in[2];
    const void* W_hh   = d_in[3];
    const void* b_ih   = d_in[4];
    const void* b_hh   = d_in[5];
    const void* W_proj = d_in[6];
    const void* b_proj = d_in[7];

    const int N = in_sizes[1];          // 100000 nodes
    const int B = B_GR;                 // 256 graphs

    // workspace carve-up (1 KiB aligned)
    char* p = (char*)d_ws;
    size_t used = 0;
    auto carve = [&](size_t bytes) {
        void* r = (void*)p;
        size_t a = (bytes + 1023) & ~(size_t)1023;
        p += a;
        used += a;
        return r;
    };
    float*  gates = (float*)carve((size_t)B * FOURD * 4);   // 2 MiB
    float*  c_buf = (float*)carve((size_t)B * D * 4);       // 512 KiB
    float*  h_buf = (float*)carve((size_t)B * D * 4);       // 512 KiB
    float*  e_ws  = (float*)carve((size_t)N * 4);           // ~391 KiB
    bf16_t* Abuf  = (bf16_t*)carve((size_t)B * KCAT * 2);   // 768 KiB
    int*    seg   = (int*)carve((size_t)(B + 1) * 4);
    int*    flags = (int*)carve(8);

    if (used > ws_size) return;   // diagnostic: zero output => err 5.703e-1

    hipMemsetAsync(c_buf, 0, (size_t)B * D * 4, stream);
    hipMemsetAsync(Abuf, 0, (size_t)B * KCAT * 2, stream);
    hipMemsetAsync(flags, 0, 8, stream);

    detect_kernel<<<1, 256, 0, stream>>>((const int*)batch, N,
                                         (const unsigned short*)x, flags);
    seg_bounds_kernel<<<(N + 255) / 256, 256, 0, stream>>>(batch, N, B, flags, seg);

    for (int step = 0; step < 3; ++step) {
        // gates = [q_star | h] @ [W_ih | W_hh]^T + b_ih + b_hh
        gemm_bt<<<dim3(FOURD / 16, B / 16), 64, 0, stream>>>(
            Abuf, KCAT, W_ih, 1024, W_hh, 512, 1024, KCAT,
            b_ih, b_hh, gates, nullptr, FOURD, flags);

        lstm_cell<<<(B * D) / 256, 256, 0, stream>>>(gates, c_buf, h_buf, Abuf);

        attention_kernel<<<B, 512, 0, stream>>>(x, N, seg, h_buf, e_ws, Abuf, flags);
    }

    // out = q_star @ W_proj^T + b_proj; output dtype follows input dtype
    gemm_bt<<<dim3(256 / 16, B / 16), 64, 0, stream>>>(
        Abuf, KCAT, W_proj, 1024, nullptr, 0, 1024, 1024,
        b_proj, nullptr, (float*)d_out, (bf16_t*)d_out, 256, flags);
}

// Round 5
// 490.176 us; speedup vs baseline: 1.9163x; 1.9163x over previous
//
#include <hip/hip_runtime.h>
#include <hip/hip_bf16.h>

// ---------------------------------------------------------------------------
// Set2Set pooling: 3 steps of { LSTM cell -> fused segment softmax attention }
// then a final projection.  B=256 graphs, N=100000 nodes, d=512.
//
// NO hipMemsetAsync and NO cross-call state: every workspace byte that is
// read is plain-written earlier in the same kernel_launch call.  Step 0 is
// specialized (q_star=h=c=0 analytically), so c/Abuf need no zero-init and
// the step-0 gates GEMM is skipped.  flags are plain-stored via a two-stage
// reduction (no atomicOr onto pre-zeroed memory).
// Runtime dtype detection: flags[0] = batch int64, flags[1] = floats are fp32.
// ---------------------------------------------------------------------------

typedef __bf16 bf16_t;
typedef __bf16 bf16x8 __attribute__((ext_vector_type(8)));
typedef float  f32x4  __attribute__((ext_vector_type(4)));

#define D     512
#define B_GR  256
#define FOURD 2048
#define KCAT  1536
#define AWAVES 16     // waves per attention block (1024 threads)
#define DET_BLOCKS 400

// ---------------------------------------------------------------------------
// Stage 1: per-block detection partials (every slot written -> no init needed)
// partA: batch looks int64 (int32 view of sorted data strictly decreases)
// partB: x looks fp32 (bf16 view of fp32 bits has |v|>=128 / NaN exponents)
__global__ void detect_part1(const int* __restrict__ b32, int N,
                             const unsigned short* __restrict__ xh,
                             int* __restrict__ partA, int* __restrict__ partB) {
    __shared__ int sA, sB;
    if (threadIdx.x == 0) { sA = 0; sB = 0; }
    __syncthreads();
    int gid = blockIdx.x * blockDim.x + threadIdx.x;
    int stride = gridDim.x * blockDim.x;
    int dec = 0;
    for (int i = gid; i < N - 1; i += stride)
        if (b32[i] > b32[i + 1]) dec = 1;
    int bad = 0;
    for (int i = gid; i < 1024; i += stride) {
        unsigned e = (xh[i] >> 7) & 0xff;   // bf16 exponent field
        if (e >= 134) bad = 1;              // |v| >= 128 or NaN/Inf
    }
    if (dec) atomicOr(&sA, 1);              // LDS atomic (sA/sB inited above)
    if (bad) atomicOr(&sB, 1);
    __syncthreads();
    if (threadIdx.x == 0) { partA[blockIdx.x] = sA; partB[blockIdx.x] = sB; }
}

// Stage 2: OR-reduce partials, plain-store flags.
__global__ void detect_part2(const int* __restrict__ partA,
                             const int* __restrict__ partB, int nblk,
                             int* __restrict__ flags) {
    __shared__ int sA, sB;
    if (threadIdx.x == 0) { sA = 0; sB = 0; }
    __syncthreads();
    int a = 0, b = 0;
    for (int i = threadIdx.x; i < nblk; i += blockDim.x) {
        a |= partA[i];
        b |= partB[i];
    }
    if (a) atomicOr(&sA, 1);
    if (b) atomicOr(&sB, 1);
    __syncthreads();
    if (threadIdx.x == 0) { flags[0] = sA; flags[1] = sB; }
}

// ---------------------------------------------------------------------------
// segment boundaries from sorted batch ids (int32 or int64 per flags[0]);
// seg[0..B] is fully written every call.
__global__ void seg_bounds_kernel(const void* __restrict__ batch, int N, int B,
                                  const int* __restrict__ flags,
                                  int* __restrict__ seg) {
    int n = blockIdx.x * blockDim.x + threadIdx.x;
    if (n >= N) return;
    const int is64 = flags[0];
    const int* b32 = (const int*)batch;
    const long long* b64 = (const long long*)batch;
    int cur = is64 ? (int)b64[n] : b32[n];
    if (n == 0) {
        for (int b = 0; b <= cur && b <= B; ++b) seg[b] = 0;
    } else {
        int prev = is64 ? (int)b64[n - 1] : b32[n - 1];
        for (int b = prev + 1; b <= cur && b <= B; ++b) seg[b] = n;
    }
    if (n == N - 1) {
        for (int b = cur + 1; b <= B; ++b) seg[b] = N;
    }
}

// ---------------------------------------------------------------------------
// dtype-polymorphic fragment / bias loads
__device__ __forceinline__ bf16x8 load_frag(const void* base, int ld, int row,
                                            int k, int f32) {
    if (f32) {
        const float* p = (const float*)base + (size_t)row * ld + k;
        bf16x8 r;
#pragma unroll
        for (int j = 0; j < 8; ++j) r[j] = (bf16_t)p[j];
        return r;
    }
    return *(const bf16x8*)((const bf16_t*)base + (size_t)row * ld + k);
}

__device__ __forceinline__ float load_bias(const void* b, int i, int f32) {
    return f32 ? ((const float*)b)[i] : (float)((const bf16_t*)b)[i];
}

// ---------------------------------------------------------------------------
// C = A * B^T (+bias) with MFMA 16x16x32 bf16.  A: [M][K] bf16 (ours).
// B split:  k < ksplit -> B1[n][k] (ldb1);  k >= ksplit -> B2[n][k-ksplit].
// Output: Cf only -> f32; Cf==Cb alias -> pick by flags[1]; Cb only -> bf16.
__global__ __launch_bounds__(64)
void gemm_bt(const bf16_t* __restrict__ A, int lda,
             const void* __restrict__ B1, int ldb1,
             const void* __restrict__ B2, int ldb2, int ksplit, int K,
             const void* __restrict__ bias1, const void* __restrict__ bias2,
             float* __restrict__ Cf, bf16_t* __restrict__ Cb, int ldc,
             const int* __restrict__ flags) {
    const int f32w  = flags[1];
    const int lane  = threadIdx.x;
    const int n0    = blockIdx.x * 16;
    const int m0    = blockIdx.y * 16;
    const int rowA  = m0 + (lane & 15);
    const int rowB  = n0 + (lane & 15);
    const int kbase = (lane >> 4) * 8;

    f32x4 acc = {0.f, 0.f, 0.f, 0.f};

    const int k1 = (ksplit < K) ? ksplit : K;
    for (int k0 = 0; k0 < k1; k0 += 32) {
        int k = k0 + kbase;
        bf16x8 a = *(const bf16x8*)(A + (size_t)rowA * lda + k);
        bf16x8 b = load_frag(B1, ldb1, rowB, k, f32w);
        acc = __builtin_amdgcn_mfma_f32_16x16x32_bf16(a, b, acc, 0, 0, 0);
    }
    for (int k0 = k1; k0 < K; k0 += 32) {
        int k = k0 + kbase;
        bf16x8 a = *(const bf16x8*)(A + (size_t)rowA * lda + k);
        bf16x8 b = load_frag(B2, ldb2, rowB, k - ksplit, f32w);
        acc = __builtin_amdgcn_mfma_f32_16x16x32_bf16(a, b, acc, 0, 0, 0);
    }

    // D layout (verified m89): col = lane&15, row = (lane>>4)*4 + reg
    const int col   = lane & 15;
    const int rbase = (lane >> 4) * 4;
    float bias = 0.f;
    if (bias1) bias += load_bias(bias1, n0 + col, f32w);
    if (bias2) bias += load_bias(bias2, n0 + col, f32w);
    const bool out_f32 = Cf && (Cb == nullptr || f32w);
#pragma unroll
    for (int r = 0; r < 4; ++r) {
        int m = m0 + rbase + r;
        int n = n0 + col;
        float v = acc[r] + bias;
        if (out_f32) Cf[(size_t)m * ldc + n] = v;
        else         Cb[(size_t)m * ldc + n] = (bf16_t)v;
    }
}

// ---------------------------------------------------------------------------
// LSTM pointwise.  first=1: gates = b_ih+b_hh and c_prev = 0 analytically
// (reference step 0 with q_star=h=0) -> reads NO gates / c memory.
// Writes c, h, and h (bf16) into Abuf columns [0,512) and [1024,1536).
__global__ void lstm_cell(const float* __restrict__ gates,
                          float* __restrict__ c, float* __restrict__ h,
                          bf16_t* __restrict__ Abuf,
                          const void* __restrict__ b_ih,
                          const void* __restrict__ b_hh,
                          const int* __restrict__ flags, int first) {
    int idx = blockIdx.x * blockDim.x + threadIdx.x;   // B*D threads
    int b = idx >> 9, t = idx & 511;
    float gi, gf, gg, go, cv;
    if (first) {
        const int f32w = flags[1];
        gi = load_bias(b_ih, t,        f32w) + load_bias(b_hh, t,        f32w);
        gf = load_bias(b_ih, 512 + t,  f32w) + load_bias(b_hh, 512 + t,  f32w);
        gg = load_bias(b_ih, 1024 + t, f32w) + load_bias(b_hh, 1024 + t, f32w);
        go = load_bias(b_ih, 1536 + t, f32w) + load_bias(b_hh, 1536 + t, f32w);
        cv = 0.f;
    } else {
        const float* g = gates + (size_t)b * FOURD;
        gi = g[t]; gf = g[512 + t]; gg = g[1024 + t]; go = g[1536 + t];
        cv = c[idx];
    }
    float si = 1.f / (1.f + __expf(-gi));
    float sf = 1.f / (1.f + __expf(-gf));
    float so = 1.f / (1.f + __expf(-go));
    float tg = tanhf(gg);
    float cn = sf * cv + si * tg;
    float hn = so * tanhf(cn);
    c[idx] = cn;
    h[idx] = hn;
    bf16_t hb = (bf16_t)hn;
    Abuf[(size_t)b * KCAT + t]        = hb;
    Abuf[(size_t)b * KCAT + 1024 + t] = hb;
}

// ---------------------------------------------------------------------------
// Fused flash-style segment softmax attention: one block (16 waves) per graph,
// ONE pass over x.  Per wave: lane l owns dims [8l,8l+8); online state
// (m_w, s_w, r_w[8]).  Cross-wave combine staged through LDS.
__global__ __launch_bounds__(1024)
void attention_kernel(const void* __restrict__ xv_, int N,
                      const int* __restrict__ seg,
                      const float* __restrict__ hbuf,
                      bf16_t* __restrict__ Abuf,
                      const int* __restrict__ flags) {
    __shared__ float racc2[AWAVES][D];     // 32 KiB
    __shared__ float red_m[AWAVES], red_s[AWAVES];

    const int f32x = flags[1];
    const int b    = blockIdx.x;
    int s  = seg[b];
    int en = seg[b + 1];
    s  = (s  < 0) ? 0 : ((s  > N) ? N : s);     // defensive clamp
    en = (en < s) ? s : ((en > N) ? N : en);
    const int cnt  = en - s;
    const int tid  = threadIdx.x;
    const int wave = tid >> 6;
    const int lane = tid & 63;

    // per-lane slice of h (8 contiguous f32); same for all waves -> L1 hot
    float hl[8];
    {
        const float* hp = hbuf + ((size_t)b << 9) + lane * 8;
#pragma unroll
        for (int j = 0; j < 8; ++j) hl[j] = hp[j];
    }

    float m_w = -INFINITY, s_w = 0.f;
    float r_w[8];
#pragma unroll
    for (int j = 0; j < 8; ++j) r_w[j] = 0.f;

    for (int i = wave; i < cnt; i += AWAVES) {
        int n = s + i;
        float xf[8];
        if (f32x) {
            const float* xp = (const float*)xv_ + ((size_t)n << 9) + lane * 8;
            float4 v0 = *(const float4*)xp;
            float4 v1 = *(const float4*)(xp + 4);
            xf[0] = v0.x; xf[1] = v0.y; xf[2] = v0.z; xf[3] = v0.w;
            xf[4] = v1.x; xf[5] = v1.y; xf[6] = v1.z; xf[7] = v1.w;
        } else {
            bf16x8 xv = *(const bf16x8*)((const bf16_t*)xv_ + ((size_t)n << 9) + lane * 8);
#pragma unroll
            for (int j = 0; j < 8; ++j) xf[j] = (float)xv[j];
        }
        float d = 0.f;
#pragma unroll
        for (int j = 0; j < 8; ++j) d += xf[j] * hl[j];
#pragma unroll
        for (int off = 32; off > 0; off >>= 1) d += __shfl_xor(d, off, 64);
        // online softmax + r accumulation (all lanes hold identical d)
        float m_new = fmaxf(m_w, d);
        float alpha = __expf(m_w - m_new);   // 0 on first iter (m_w=-inf)
        float p     = __expf(d - m_new);
        s_w = s_w * alpha + p;
#pragma unroll
        for (int j = 0; j < 8; ++j) r_w[j] = r_w[j] * alpha + p * xf[j];
        m_w = m_new;
    }

    if (lane == 0) { red_m[wave] = m_w; red_s[wave] = s_w; }
    __syncthreads();

    float M = -INFINITY, S = 0.f;
#pragma unroll
    for (int w = 0; w < AWAVES; ++w)
        if (red_s[w] > 0.f) M = fmaxf(M, red_m[w]);
#pragma unroll
    for (int w = 0; w < AWAVES; ++w)
        if (red_s[w] > 0.f) S += red_s[w] * __expf(red_m[w] - M);
    float Sinv  = 1.f / (S + 1e-16f);
    float scale = (s_w > 0.f) ? __expf(m_w - M) * Sinv : 0.f;

    // stage scaled per-wave partials, then reduce across waves
#pragma unroll
    for (int j = 0; j < 8; ++j) racc2[wave][lane * 8 + j] = r_w[j] * scale;
    __syncthreads();

    if (tid < D) {
        float r = 0.f;
#pragma unroll
        for (int w = 0; w < AWAVES; ++w) r += racc2[w][tid];
        Abuf[(size_t)b * KCAT + 512 + tid] = (bf16_t)r;  // r -> A cols [512,1024)
    }
}

// ---------------------------------------------------------------------------
extern "C" void kernel_launch(void* const* d_in, const int* in_sizes, int n_in,
                              void* d_out, int out_size, void* d_ws, size_t ws_size,
                              hipStream_t stream) {
    const void* x      = d_in[0];
    const void* batch  = d_in[1];
    const void* W_ih   = d_in[2];
    const void* W_hh   = d_in[3];
    const void* b_ih   = d_in[4];
    const void* b_hh   = d_in[5];
    const void* W_proj = d_in[6];
    const void* b_proj = d_in[7];

    const int N = in_sizes[1];          // 100000 nodes
    const int B = B_GR;                 // 256 graphs

    // workspace carve-up (1 KiB aligned); nothing is read before being
    // written in this same call, so no zero-init is required anywhere.
    char* p = (char*)d_ws;
    size_t used = 0;
    auto carve = [&](size_t bytes) {
        void* r = (void*)p;
        size_t a = (bytes + 1023) & ~(size_t)1023;
        p += a;
        used += a;
        return r;
    };
    float*  gates = (float*)carve((size_t)B * FOURD * 4);   // 2 MiB
    float*  c_buf = (float*)carve((size_t)B * D * 4);       // 512 KiB
    float*  h_buf = (float*)carve((size_t)B * D * 4);       // 512 KiB
    bf16_t* Abuf  = (bf16_t*)carve((size_t)B * KCAT * 2);   // 768 KiB
    int*    seg   = (int*)carve((size_t)(B + 1) * 4);
    int*    flags = (int*)carve(8);
    int*    partA = (int*)carve(DET_BLOCKS * 4);
    int*    partB = (int*)carve(DET_BLOCKS * 4);

    if (used > ws_size) return;   // diagnostic: zero/garbage output

    detect_part1<<<DET_BLOCKS, 256, 0, stream>>>(
        (const int*)batch, N, (const unsigned short*)x, partA, partB);
    detect_part2<<<1, 512, 0, stream>>>(partA, partB, DET_BLOCKS, flags);
    seg_bounds_kernel<<<(N + 255) / 256, 256, 0, stream>>>(batch, N, B, flags, seg);

    // step 0 (specialized: q_star = h = c = 0 analytically, no gates GEMM)
    lstm_cell<<<(B * D) / 256, 256, 0, stream>>>(
        nullptr, c_buf, h_buf, Abuf, b_ih, b_hh, flags, 1);
    attention_kernel<<<B, 1024, 0, stream>>>(x, N, seg, h_buf, Abuf, flags);

    for (int step = 1; step < 3; ++step) {
        // gates = [q_star | h] @ [W_ih | W_hh]^T + b_ih + b_hh
        gemm_bt<<<dim3(FOURD / 16, B / 16), 64, 0, stream>>>(
            Abuf, KCAT, W_ih, 1024, W_hh, 512, 1024, KCAT,
            b_ih, b_hh, gates, nullptr, FOURD, flags);

        lstm_cell<<<(B * D) / 256, 256, 0, stream>>>(
            gates, c_buf, h_buf, Abuf, b_ih, b_hh, flags, 0);

        attention_kernel<<<B, 1024, 0, stream>>>(x, N, seg, h_buf, Abuf, flags);
    }

    // out = q_star @ W_proj^T + b_proj; output dtype follows input dtype
    gemm_bt<<<dim3(256 / 16, B / 16), 64, 0, stream>>>(
        Abuf, KCAT, W_proj, 1024, nullptr, 0, 1024, 1024,
        b_proj, nullptr, (float*)d_out, (bf16_t*)d_out, 256, flags);
}

// Round 6
// 424.195 us; speedup vs baseline: 2.2144x; 1.1555x over previous
//
#include <hip/hip_runtime.h>
#include <hip/hip_bf16.h>

// ---------------------------------------------------------------------------
// Set2Set pooling: 3 steps of { LSTM cell -> fused segment softmax attention }
// then a final projection.  B=256 graphs, N=100000 nodes, d=512.
//
// Round-6 structure (inputs detected fp32 at runtime; bf16 also supported):
//   prep      : W_ih|W_hh -> Wcat bf16 [2048][1536]; W_proj -> bf16; bias sums f32
//   lstm0     : step-0 LSTM specialization (gates = b_ih+b_hh, c=0 analytically)
//   attn step0: flash-style softmax-attention pass over x (fp32), fused cast of
//               x -> xb (bf16) for later steps; r -> Abuf0
//   gemm_lstm : gates GEMM (MFMA bf16, 4 gate tiles per block) with the LSTM
//               pointwise fused in the epilogue; h -> h_buf + AbufOut (ping-pong)
//   attn 1,2  : read xb (bf16)
//   proj      : out = q_star @ W_proj^T + b_proj
// No memsets, no cross-call state: every byte read is written earlier in-call.
// ---------------------------------------------------------------------------

typedef __bf16 bf16_t;
typedef __bf16 bf16x8 __attribute__((ext_vector_type(8)));
typedef float  f32x4  __attribute__((ext_vector_type(4)));

#define D     512
#define B_GR  256
#define FOURD 2048
#define KCAT  1536
#define AWAVES 16     // waves per attention block (1024 threads)
#define DET_BLOCKS 400

// ---------------------------------------------------------------------------
__device__ __forceinline__ float load_f(const void* b, int i, int f32) {
    return f32 ? ((const float*)b)[i] : (float)((const bf16_t*)b)[i];
}

// ---------------------------------------------------------------------------
// Stage 1: per-block detection partials (every slot written -> no init needed)
__global__ void detect_part1(const int* __restrict__ b32, int N,
                             const unsigned short* __restrict__ xh,
                             int* __restrict__ partA, int* __restrict__ partB) {
    __shared__ int sA, sB;
    if (threadIdx.x == 0) { sA = 0; sB = 0; }
    __syncthreads();
    int gid = blockIdx.x * blockDim.x + threadIdx.x;
    int stride = gridDim.x * blockDim.x;
    int dec = 0;
    for (int i = gid; i < N - 1; i += stride)
        if (b32[i] > b32[i + 1]) dec = 1;       // int64-as-int32 signature
    int bad = 0;
    for (int i = gid; i < 1024; i += stride) {
        unsigned e = (xh[i] >> 7) & 0xff;        // bf16 exponent field
        if (e >= 134) bad = 1;                   // fp32-bits-as-bf16 signature
    }
    if (dec) atomicOr(&sA, 1);
    if (bad) atomicOr(&sB, 1);
    __syncthreads();
    if (threadIdx.x == 0) { partA[blockIdx.x] = sA; partB[blockIdx.x] = sB; }
}

// Stage 2: OR-reduce partials, plain-store flags (flags[0]=int64, [1]=fp32).
__global__ void detect_part2(const int* __restrict__ partA,
                             const int* __restrict__ partB, int nblk,
                             int* __restrict__ flags) {
    __shared__ int sA, sB;
    if (threadIdx.x == 0) { sA = 0; sB = 0; }
    __syncthreads();
    int a = 0, b = 0;
    for (int i = threadIdx.x; i < nblk; i += blockDim.x) {
        a |= partA[i];
        b |= partB[i];
    }
    if (a) atomicOr(&sA, 1);
    if (b) atomicOr(&sB, 1);
    __syncthreads();
    if (threadIdx.x == 0) { flags[0] = sA; flags[1] = sB; }
}

// ---------------------------------------------------------------------------
// segment boundaries from sorted batch ids; seg[0..B] fully written every call
__global__ void seg_bounds_kernel(const void* __restrict__ batch, int N, int B,
                                  const int* __restrict__ flags,
                                  int* __restrict__ seg) {
    int n = blockIdx.x * blockDim.x + threadIdx.x;
    if (n >= N) return;
    const int is64 = flags[0];
    const int* b32 = (const int*)batch;
    const long long* b64 = (const long long*)batch;
    int cur = is64 ? (int)b64[n] : b32[n];
    if (n == 0) {
        for (int b = 0; b <= cur && b <= B; ++b) seg[b] = 0;
    } else {
        int prev = is64 ? (int)b64[n - 1] : b32[n - 1];
        for (int b = prev + 1; b <= cur && b <= B; ++b) seg[b] = n;
    }
    if (n == N - 1) {
        for (int b = cur + 1; b <= B; ++b) seg[b] = N;
    }
}

// ---------------------------------------------------------------------------
// Weight prep: Wcat[r][k] = k<1024 ? W_ih[r][k] : W_hh[r][k-1024] (bf16);
// Wp = W_proj bf16; bsum = b_ih+b_hh (f32); bp = b_proj (f32).
#define WCAT_E (FOURD * KCAT)
#define WP_E   (256 * 1024)
__global__ void prep_kernel(const void* __restrict__ W_ih,
                            const void* __restrict__ W_hh,
                            const void* __restrict__ b_ih,
                            const void* __restrict__ b_hh,
                            const void* __restrict__ W_proj,
                            const void* __restrict__ b_proj,
                            const int* __restrict__ flags,
                            bf16_t* __restrict__ Wcat, bf16_t* __restrict__ Wp,
                            float* __restrict__ bsum, float* __restrict__ bp) {
    const int f32 = flags[1];
    int gid = blockIdx.x * blockDim.x + threadIdx.x;
    int stride = gridDim.x * blockDim.x;
    const int total = WCAT_E + WP_E + FOURD + 256;
    for (int idx = gid; idx < total; idx += stride) {
        if (idx < WCAT_E) {
            int r = idx / KCAT, k = idx - r * KCAT;
            float v = (k < 1024) ? load_f(W_ih, r * 1024 + k, f32)
                                 : load_f(W_hh, r * 512 + (k - 1024), f32);
            Wcat[idx] = (bf16_t)v;
        } else if (idx < WCAT_E + WP_E) {
            int j = idx - WCAT_E;
            Wp[j] = (bf16_t)load_f(W_proj, j, f32);
        } else if (idx < WCAT_E + WP_E + FOURD) {
            int i = idx - WCAT_E - WP_E;
            bsum[i] = load_f(b_ih, i, f32) + load_f(b_hh, i, f32);
        } else {
            int i = idx - WCAT_E - WP_E - FOURD;
            bp[i] = load_f(b_proj, i, f32);
        }
    }
}

// ---------------------------------------------------------------------------
// Step-0 LSTM: gates = bsum, c_prev = 0 analytically.  Writes c, h, and h
// (bf16) into Abuf cols [0,512) and [1024,1536).
__global__ void lstm0_kernel(const float* __restrict__ bsum,
                             float* __restrict__ c, float* __restrict__ h,
                             bf16_t* __restrict__ Abuf) {
    int idx = blockIdx.x * blockDim.x + threadIdx.x;   // B*D threads
    int b = idx >> 9, t = idx & 511;
    float gi = bsum[t], gf = bsum[512 + t], gg = bsum[1024 + t], go = bsum[1536 + t];
    (void)gf;
    float si = 1.f / (1.f + __expf(-gi));
    float so = 1.f / (1.f + __expf(-go));
    float tg = tanhf(gg);
    float cn = si * tg;                 // sigmoid(f)*0 + sigmoid(i)*tanh(g)
    float hn = so * tanhf(cn);
    c[idx] = cn;
    h[idx] = hn;
    bf16_t hb = (bf16_t)hn;
    Abuf[(size_t)b * KCAT + t]        = hb;
    Abuf[(size_t)b * KCAT + 1024 + t] = hb;
}

// ---------------------------------------------------------------------------
// Fused gates-GEMM + LSTM pointwise.  One wave per (16 t-cols x 16 graphs);
// computes all 4 gate tiles (i,f,g,o) so the LSTM update happens in-register.
// Reads AbufIn (q_star||h), writes c (in-place), h_buf, and h->AbufOut.
__global__ __launch_bounds__(64)
void gemm_lstm(const bf16_t* __restrict__ AbufIn,
               const bf16_t* __restrict__ Wcat,
               const float* __restrict__ bsum,
               float* __restrict__ c, float* __restrict__ h,
               bf16_t* __restrict__ AbufOut) {
    const int lane  = threadIdx.x;
    const int t0    = blockIdx.x * 16;       // col within [0,512)
    const int m0    = blockIdx.y * 16;       // graph tile
    const int rowA  = m0 + (lane & 15);
    const int colB  = t0 + (lane & 15);
    const int kbase = (lane >> 4) * 8;

    f32x4 acc[4] = {{0,0,0,0},{0,0,0,0},{0,0,0,0},{0,0,0,0}};

    for (int k0 = 0; k0 < KCAT; k0 += 32) {
        int k = k0 + kbase;
        bf16x8 a = *(const bf16x8*)(AbufIn + (size_t)rowA * KCAT + k);
#pragma unroll
        for (int g = 0; g < 4; ++g) {
            bf16x8 bfr = *(const bf16x8*)(Wcat + (size_t)(g * 512 + colB) * KCAT + k);
            acc[g] = __builtin_amdgcn_mfma_f32_16x16x32_bf16(a, bfr, acc[g], 0, 0, 0);
        }
    }

    // D layout (verified m89): col = lane&15, row = (lane>>4)*4 + reg
    const int col   = colB;
    const int rbase = (lane >> 4) * 4;
    float bi = bsum[col], bf = bsum[512 + col], bg = bsum[1024 + col], bo = bsum[1536 + col];
#pragma unroll
    for (int r = 0; r < 4; ++r) {
        int m = m0 + rbase + r;
        float gi = acc[0][r] + bi;
        float gf = acc[1][r] + bf;
        float gg = acc[2][r] + bg;
        float go = acc[3][r] + bo;
        size_t ci = (size_t)m * D + col;
        float cv = c[ci];
        float si = 1.f / (1.f + __expf(-gi));
        float sf = 1.f / (1.f + __expf(-gf));
        float so = 1.f / (1.f + __expf(-go));
        float tg = tanhf(gg);
        float cn = sf * cv + si * tg;
        float hn = so * tanhf(cn);
        c[ci] = cn;
        h[ci] = hn;
        bf16_t hb = (bf16_t)hn;
        AbufOut[(size_t)m * KCAT + col]        = hb;
        AbufOut[(size_t)m * KCAT + 1024 + col] = hb;
    }
}

// ---------------------------------------------------------------------------
// row loaders for attention
__device__ __forceinline__ void load_row_f32(const float* xp, float* xf) {
    float4 v0 = *(const float4*)xp;
    float4 v1 = *(const float4*)(xp + 4);
    xf[0] = v0.x; xf[1] = v0.y; xf[2] = v0.z; xf[3] = v0.w;
    xf[4] = v1.x; xf[5] = v1.y; xf[6] = v1.z; xf[7] = v1.w;
}
__device__ __forceinline__ void load_row_bf16(const bf16_t* xp, float* xf) {
    bf16x8 v = *(const bf16x8*)xp;
#pragma unroll
    for (int j = 0; j < 8; ++j) xf[j] = (float)v[j];
}

// ---------------------------------------------------------------------------
// Fused flash-style segment softmax attention: one block (16 waves) per graph,
// ONE pass over x, 2 nodes per wave-iteration.  In step0 with fp32 input, also
// casts x into xb (bf16) for the later steps.
__global__ __launch_bounds__(1024)
void attention_kernel(const void* __restrict__ x, bf16_t* __restrict__ xb,
                      int use_xb, int step0, int N,
                      const int* __restrict__ seg,
                      const float* __restrict__ hbuf,
                      bf16_t* __restrict__ AbufOut,
                      const int* __restrict__ flags) {
    __shared__ float racc2[AWAVES][D];     // 32 KiB
    __shared__ float red_m[AWAVES], red_s[AWAVES];

    const int f32x = flags[1];
    const bool rd32 = f32x && (step0 || !use_xb);
    const void* xsrc = rd32 ? x : (f32x ? (const void*)xb : x);
    const bool wrxb = f32x && step0 && use_xb;

    const int b = blockIdx.x;
    int s  = seg[b];
    int en = seg[b + 1];
    s  = (s  < 0) ? 0 : ((s  > N) ? N : s);     // defensive clamp
    en = (en < s) ? s : ((en > N) ? N : en);
    const int cnt  = en - s;
    const int tid  = threadIdx.x;
    const int wave = tid >> 6;
    const int lane = tid & 63;

    // per-lane slice of h (8 contiguous f32); same for all waves -> L1 hot
    float hl[8];
    {
        const float* hp = hbuf + ((size_t)b << 9) + lane * 8;
#pragma unroll
        for (int j = 0; j < 8; ++j) hl[j] = hp[j];
    }

    float m_w = -INFINITY, s_w = 0.f;
    float r_w[8];
#pragma unroll
    for (int j = 0; j < 8; ++j) r_w[j] = 0.f;

    for (int i = 2 * wave; i < cnt; i += 2 * AWAVES) {
        int n1 = s + i;
        bool has2 = (i + 1) < cnt;
        float x1[8], x2[8];
        size_t off1 = ((size_t)n1 << 9) + lane * 8;
        size_t off2 = off1 + D;
        if (rd32) {
            load_row_f32((const float*)xsrc + off1, x1);
            if (has2) load_row_f32((const float*)xsrc + off2, x2);
        } else {
            load_row_bf16((const bf16_t*)xsrc + off1, x1);
            if (has2) load_row_bf16((const bf16_t*)xsrc + off2, x2);
        }
        if (!has2) {
#pragma unroll
            for (int j = 0; j < 8; ++j) x2[j] = 0.f;
        }
        if (wrxb) {
            bf16x8 v1;
#pragma unroll
            for (int j = 0; j < 8; ++j) v1[j] = (bf16_t)x1[j];
            *(bf16x8*)(xb + off1) = v1;
            if (has2) {
                bf16x8 v2;
#pragma unroll
                for (int j = 0; j < 8; ++j) v2[j] = (bf16_t)x2[j];
                *(bf16x8*)(xb + off2) = v2;
            }
        }
        float d1 = 0.f, d2 = 0.f;
#pragma unroll
        for (int j = 0; j < 8; ++j) { d1 += x1[j] * hl[j]; d2 += x2[j] * hl[j]; }
#pragma unroll
        for (int off = 32; off > 0; off >>= 1) {
            d1 += __shfl_xor(d1, off, 64);
            d2 += __shfl_xor(d2, off, 64);
        }
        if (!has2) d2 = -INFINITY;
        // combined online-softmax update (all lanes hold identical d1,d2)
        float m12   = fmaxf(d1, d2);
        float m_new = fmaxf(m_w, m12);
        float alpha = __expf(m_w - m_new);   // 0 on first iter (m_w=-inf)
        float p1    = __expf(d1 - m_new);
        float p2    = __expf(d2 - m_new);    // 0 when !has2
        s_w = s_w * alpha + p1 + p2;
#pragma unroll
        for (int j = 0; j < 8; ++j)
            r_w[j] = r_w[j] * alpha + p1 * x1[j] + p2 * x2[j];
        m_w = m_new;
    }

    if (lane == 0) { red_m[wave] = m_w; red_s[wave] = s_w; }
    __syncthreads();

    float M = -INFINITY, S = 0.f;
#pragma unroll
    for (int w = 0; w < AWAVES; ++w)
        if (red_s[w] > 0.f) M = fmaxf(M, red_m[w]);
#pragma unroll
    for (int w = 0; w < AWAVES; ++w)
        if (red_s[w] > 0.f) S += red_s[w] * __expf(red_m[w] - M);
    float Sinv  = 1.f / (S + 1e-16f);
    float scale = (s_w > 0.f) ? __expf(m_w - M) * Sinv : 0.f;

#pragma unroll
    for (int j = 0; j < 8; ++j) racc2[wave][lane * 8 + j] = r_w[j] * scale;
    __syncthreads();

    if (tid < D) {
        float r = 0.f;
#pragma unroll
        for (int w = 0; w < AWAVES; ++w) r += racc2[w][tid];
        AbufOut[(size_t)b * KCAT + 512 + tid] = (bf16_t)r;  // r -> cols [512,1024)
    }
}

// ---------------------------------------------------------------------------
// out = q_star @ W_proj^T + b_proj.  M=256 graphs, N=256, K=1024 (lda=KCAT).
__global__ __launch_bounds__(64)
void gemm_proj(const bf16_t* __restrict__ A,
               const bf16_t* __restrict__ Wp, const float* __restrict__ bp,
               void* __restrict__ out, const int* __restrict__ flags) {
    const int f32o  = flags[1];
    const int lane  = threadIdx.x;
    const int n0    = blockIdx.x * 16;
    const int m0    = blockIdx.y * 16;
    const int rowA  = m0 + (lane & 15);
    const int rowB  = n0 + (lane & 15);
    const int kbase = (lane >> 4) * 8;

    f32x4 acc = {0.f, 0.f, 0.f, 0.f};
    for (int k0 = 0; k0 < 1024; k0 += 32) {
        int k = k0 + kbase;
        bf16x8 a = *(const bf16x8*)(A  + (size_t)rowA * KCAT + k);
        bf16x8 b = *(const bf16x8*)(Wp + (size_t)rowB * 1024 + k);
        acc = __builtin_amdgcn_mfma_f32_16x16x32_bf16(a, b, acc, 0, 0, 0);
    }
    const int col   = n0 + (lane & 15);
    const int rbase = (lane >> 4) * 4;
    float bias = bp[col];
#pragma unroll
    for (int r = 0; r < 4; ++r) {
        int m = m0 + rbase + r;
        float v = acc[r] + bias;
        if (f32o) ((float*)out)[(size_t)m * 256 + col]  = v;
        else      ((bf16_t*)out)[(size_t)m * 256 + col] = (bf16_t)v;
    }
}

// ---------------------------------------------------------------------------
extern "C" void kernel_launch(void* const* d_in, const int* in_sizes, int n_in,
                              void* d_out, int out_size, void* d_ws, size_t ws_size,
                              hipStream_t stream) {
    const void* x      = d_in[0];
    const void* batch  = d_in[1];
    const void* W_ih   = d_in[2];
    const void* W_hh   = d_in[3];
    const void* b_ih   = d_in[4];
    const void* b_hh   = d_in[5];
    const void* W_proj = d_in[6];
    const void* b_proj = d_in[7];

    const int N = in_sizes[1];          // 100000 nodes
    const int B = B_GR;                 // 256 graphs

    // workspace carve-up (1 KiB aligned); nothing read before written in-call
    char* p = (char*)d_ws;
    size_t used = 0;
    auto carve = [&](size_t bytes) {
        void* r = (void*)p;
        size_t a = (bytes + 1023) & ~(size_t)1023;
        p += a;
        used += a;
        return r;
    };
    float*  c_buf = (float*)carve((size_t)B * D * 4);
    float*  h_buf = (float*)carve((size_t)B * D * 4);
    bf16_t* Abuf0 = (bf16_t*)carve((size_t)B * KCAT * 2);
    bf16_t* Abuf1 = (bf16_t*)carve((size_t)B * KCAT * 2);
    bf16_t* Wcat  = (bf16_t*)carve((size_t)FOURD * KCAT * 2);  // 6 MiB
    bf16_t* Wp    = (bf16_t*)carve((size_t)256 * 1024 * 2);
    float*  bsum  = (float*)carve((size_t)FOURD * 4);
    float*  bp    = (float*)carve((size_t)256 * 4);
    int*    seg   = (int*)carve((size_t)(B + 1) * 4);
    int*    flags = (int*)carve(8);
    int*    partA = (int*)carve(DET_BLOCKS * 4);
    int*    partB = (int*)carve(DET_BLOCKS * 4);
    if (used > ws_size) return;
    bf16_t* xb = (bf16_t*)carve((size_t)N * D * 2);            // ~100 MiB
    int use_xb = (used <= ws_size) ? 1 : 0;

    detect_part1<<<DET_BLOCKS, 256, 0, stream>>>(
        (const int*)batch, N, (const unsigned short*)x, partA, partB);
    detect_part2<<<1, 512, 0, stream>>>(partA, partB, DET_BLOCKS, flags);
    seg_bounds_kernel<<<(N + 255) / 256, 256, 0, stream>>>(batch, N, B, flags, seg);
    prep_kernel<<<1024, 256, 0, stream>>>(W_ih, W_hh, b_ih, b_hh, W_proj, b_proj,
                                          flags, Wcat, Wp, bsum, bp);

    // step 0: specialized LSTM (no GEMM), attention fused with x->bf16 cast
    lstm0_kernel<<<(B * D) / 256, 256, 0, stream>>>(bsum, c_buf, h_buf, Abuf0);
    attention_kernel<<<B, 1024, 0, stream>>>(x, xb, use_xb, 1, N, seg,
                                             h_buf, Abuf0, flags);

    // step 1
    gemm_lstm<<<dim3(D / 16, B / 16), 64, 0, stream>>>(
        Abuf0, Wcat, bsum, c_buf, h_buf, Abuf1);
    attention_kernel<<<B, 1024, 0, stream>>>(x, xb, use_xb, 0, N, seg,
                                             h_buf, Abuf1, flags);
    // step 2
    gemm_lstm<<<dim3(D / 16, B / 16), 64, 0, stream>>>(
        Abuf1, Wcat, bsum, c_buf, h_buf, Abuf0);
    attention_kernel<<<B, 1024, 0, stream>>>(x, xb, use_xb, 0, N, seg,
                                             h_buf, Abuf0, flags);

    // projection
    gemm_proj<<<dim3(256 / 16, B / 16), 64, 0, stream>>>(Abuf0, Wp, bp, d_out, flags);
}